// Round 16
// baseline (647.823 us; speedup 1.0000x reference)
//
#include <hip/hip_runtime.h>
#include <hip/hip_fp16.h>
#include <math.h>
#include <stdint.h>

#define NN 50000
#define NE 800000
#define ET (NE + NN)      // 850000 edges incl self loops
#define FIN 128
#define DD 250
#define HD 256
#define NQ 200000
#define NEG_SLOPE 0.2f

typedef unsigned short u16;
typedef __attribute__((ext_vector_type(8))) short bf16x8;
typedef __attribute__((ext_vector_type(4))) float f32x4;
typedef _Float16 h2v __attribute__((ext_vector_type(2)));

__device__ __forceinline__ u16 f2bf_rne(float x) {
    unsigned int b = __float_as_uint(x);
    unsigned int r = (b + 0x7FFFu + ((b >> 16) & 1u)) >> 16;
    return (u16)r;
}
__device__ __forceinline__ void split2(float v, u16& h, u16& l) {
    unsigned int b = __float_as_uint(v);
    h = (u16)(b >> 16);
    float r = v - __uint_as_float(b & 0xFFFF0000u);
    l = f2bf_rne(r);
}
__device__ __forceinline__ u16 f2h(float v) {
    __half h = __float2half(v);
    return *reinterpret_cast<u16*>(&h);
}
// load 4 fp16 (8B) -> float4 (used by query kernel)
__device__ __forceinline__ float4 ld4h(const u16* p) {
    uint2 r = *(const uint2*)p;
    __half2 a = *(__half2*)&r.x;
    __half2 b = *(__half2*)&r.y;
    float2 fa = __half22float2(a), fb = __half22float2(b);
    return make_float4(fa.x, fa.y, fb.x, fb.y);
}
// packed fp16 max -> v_pk_max_f16 (avoids ROCm __hmax2 header overload issues)
__device__ __forceinline__ h2v hmax2v(h2v a, h2v b) {
    return __builtin_elementwise_max(a, b);
}

// ---------------- CSR build ----------------

__global__ void count_kernel(const int* __restrict__ ei, int* __restrict__ cnt) {
    int k = blockIdx.x * 256 + threadIdx.x;
    if (k >= ET) return;
    int d = (k < NE) ? ei[NE + k] : (k - NE);
    atomicAdd(&cnt[d], 1);
}

__global__ __launch_bounds__(256) void scan1_kernel(
    int* __restrict__ cnt, int* __restrict__ rowptr, int* __restrict__ bsum)
{
    __shared__ int buf[256];
    int t = threadIdx.x;
    int i = blockIdx.x * 256 + t;
    int v = (i < NN) ? cnt[i] : 0;
    if (i < NN) cnt[i] = 0;          // zero fill for scatter
    buf[t] = v;
    __syncthreads();
#pragma unroll
    for (int off = 1; off < 256; off <<= 1) {
        int add = (t >= off) ? buf[t - off] : 0;
        __syncthreads();
        buf[t] += add;
        __syncthreads();
    }
    if (i < NN) rowptr[i] = buf[t] - v;     // block-local exclusive
    if (t == 255) bsum[blockIdx.x] = buf[255];
}

__global__ __launch_bounds__(256) void scan2_kernel(
    int* __restrict__ bsum, int* __restrict__ rowptr, int nb)
{
    __shared__ int buf[256];
    int t = threadIdx.x;
    int v = (t < nb) ? bsum[t] : 0;
    buf[t] = v;
    __syncthreads();
#pragma unroll
    for (int off = 1; off < 256; off <<= 1) {
        int add = (t >= off) ? buf[t - off] : 0;
        __syncthreads();
        buf[t] += add;
        __syncthreads();
    }
    if (t < nb) bsum[t] = buf[t] - v;
    if (t == 255) rowptr[NN] = buf[255];
}

__global__ __launch_bounds__(256) void scan3_kernel(
    int* __restrict__ rowptr, const int* __restrict__ bsum)
{
    int i = blockIdx.x * 256 + threadIdx.x;
    if (i < NN) rowptr[i] += bsum[blockIdx.x];
}

// stores premultiplied src BYTE offset (s*512, fp16-row stride) for the fused kernel
__global__ void scatter_kernel(const int* __restrict__ ei,
                               const int* __restrict__ rowptr,
                               int* __restrict__ fill,
                               int* __restrict__ ssrc) {
    int k = blockIdx.x * 256 + threadIdx.x;
    if (k >= ET) return;
    int s, d;
    if (k < NE) { s = ei[k]; d = ei[NE + k]; }
    else        { s = k - NE; d = k - NE; }
    int pos = rowptr[d] + atomicAdd(&fill[d], 1);
    ssrc[pos] = s << 9;
}

// ---------------- combined conversion kernel ----------------

#define CONVX_BLOCKS 3125

__global__ __launch_bounds__(256) void conv_all(
    const float* __restrict__ x, int* __restrict__ fill,
    u16* __restrict__ Ah, u16* __restrict__ Al,
    const float* __restrict__ W1l, const float* __restrict__ W1r,
    const float* __restrict__ W2l, const float* __restrict__ W2r,
    const float* __restrict__ Wm1,
    u16* __restrict__ W1lTh, u16* __restrict__ W1lTl,
    u16* __restrict__ W1rTh, u16* __restrict__ W1rTl,
    u16* __restrict__ W2lTh, u16* __restrict__ W2lTl,
    u16* __restrict__ W2rTh, u16* __restrict__ W2rTl,
    u16* __restrict__ WmtTh, u16* __restrict__ WmtTl,
    u16* __restrict__ WmbTh, u16* __restrict__ WmbTl)
{
    if (blockIdx.x < CONVX_BLOCKS) {
        int tid = blockIdx.x * 256 + threadIdx.x;
        if (tid < NN) fill[tid] = 0;
        size_t idx = (size_t)tid * 8;
        if (idx >= (size_t)NN * FIN) return;
        float4 v0 = *(const float4*)(x + idx);
        float4 v1 = *(const float4*)(x + idx + 4);
        float vv[8] = {v0.x, v0.y, v0.z, v0.w, v1.x, v1.y, v1.z, v1.w};
        bf16x8 h, l;
#pragma unroll
        for (int j = 0; j < 8; j++) {
            u16 hh, ll;
            split2(vv[j], hh, ll);
            h[j] = (short)hh; l[j] = (short)ll;
        }
        *(bf16x8*)(Ah + idx) = h;
        *(bf16x8*)(Al + idx) = l;
        return;
    }
    int b = blockIdx.x - CONVX_BLOCKS;
    const float* W; int K, N, koff, kshift, b0; u16 *oh, *ol;
    if (b < 128)       { W = W1l; K = FIN; N = DD; koff = 0;  kshift = 7; b0 = 0;    oh = W1lTh; ol = W1lTl; }
    else if (b < 256)  { W = W1r; K = FIN; N = DD; koff = 0;  kshift = 7; b0 = 128;  oh = W1rTh; ol = W1rTl; }
    else if (b < 512)  { W = W2l; K = DD;  N = DD; koff = 0;  kshift = 8; b0 = 256;  oh = W2lTh; ol = W2lTl; }
    else if (b < 768)  { W = W2r; K = DD;  N = DD; koff = 0;  kshift = 8; b0 = 512;  oh = W2rTh; ol = W2rTl; }
    else if (b < 1024) { W = Wm1; K = DD;  N = HD; koff = 0;  kshift = 8; b0 = 768;  oh = WmtTh; ol = WmtTl; }
    else               { W = Wm1; K = DD;  N = HD; koff = DD; kshift = 8; b0 = 1024; oh = WmbTh; ol = WmbTl; }
    int id = (b - b0) * 256 + threadIdx.x;
    int Kp = 1 << kshift;
    int n = id >> kshift, k = id & (Kp - 1);
    float v = (n < N && k < K) ? W[(size_t)(k + koff) * N + n] : 0.f;
    u16 h, l;
    split2(v, h, l);
    oh[id] = h;
    ol[id] = l;
}

// ---------------- pre-split bf16 MFMA pair-GEMM ----------------
// A staged in LDS (rows padded 32->40 u16: conflict-free b128 writes/reads).
// B fragments read directly from global per K-step (weights are shared by all
// row-blocks -> L1/L2-resident; removes 2/3 of LDS traffic and half the barrier load).
// fmt bit0: C0 as fp16 stride-256; bit1: C1 as fp16 stride-256; else fp32 stride-N

#define AP 40   // padded A row length (u16)

__global__ __launch_bounds__(256, 2) void gemm_pair(
    const u16* __restrict__ Ah, const u16* __restrict__ Al, int Kp,
    const u16* __restrict__ B0h, const u16* __restrict__ B0l,
    const u16* __restrict__ B1h, const u16* __restrict__ B1l,
    const float* __restrict__ bias0, const float* __restrict__ bias1,
    void* __restrict__ C0v, void* __restrict__ C1v, int M, int N, int fmt)
{
    __shared__ u16 AhS[128][AP], AlS[128][AP];

    int row0 = blockIdx.x * 128;
    int col0 = blockIdx.y * 128;
    int t = threadIdx.x;
    int lane = t & 63, w = t >> 6;
    int wr = w >> 1, wc = w & 1;
    int quad = lane >> 4, rr = lane & 15;

    f32x4 acc0[4][4], acc1[4][4];
#pragma unroll
    for (int i = 0; i < 4; i++)
#pragma unroll
        for (int j = 0; j < 4; j++) {
            acc0[i][j] = (f32x4){0.f, 0.f, 0.f, 0.f};
            acc1[i][j] = (f32x4){0.f, 0.f, 0.f, 0.f};
        }

    int ar = t >> 1, akh = (t & 1) * 16;
    int gr = row0 + ar;
    const u16* pAh = Ah + (size_t)gr * Kp + akh;
    const u16* pAl = Al + (size_t)gr * Kp + akh;

    // per-lane element offsets into the B arrays (one per fj; shared by all 4 arrays)
    size_t boff[4];
#pragma unroll
    for (int fj = 0; fj < 4; fj++)
        boff[fj] = (size_t)(col0 + wc * 64 + fj * 16 + rr) * Kp + quad * 8;

    for (int k0 = 0; k0 < Kp; k0 += 32) {
        bf16x8 ah0{}, ah1{}, al0{}, al1{};
        if (gr < M) {
            ah0 = *(const bf16x8*)(pAh + k0);
            ah1 = *(const bf16x8*)(pAh + k0 + 8);
            al0 = *(const bf16x8*)(pAl + k0);
            al1 = *(const bf16x8*)(pAl + k0 + 8);
        }
        *(bf16x8*)&AhS[ar][akh]     = ah0;
        *(bf16x8*)&AhS[ar][akh + 8] = ah1;
        *(bf16x8*)&AlS[ar][akh]     = al0;
        *(bf16x8*)&AlS[ar][akh + 8] = al1;
        __syncthreads();

        bf16x8 fAh[4], fAl[4];
#pragma unroll
        for (int fi = 0; fi < 4; fi++) {
            int r = wr * 64 + fi * 16 + rr;
            fAh[fi] = *(const bf16x8*)&AhS[r][quad * 8];
            fAl[fi] = *(const bf16x8*)&AlS[r][quad * 8];
        }
#pragma unroll
        for (int fj = 0; fj < 4; fj++) {
            bf16x8 b0h = *(const bf16x8*)(B0h + boff[fj] + k0);
            bf16x8 b0l = *(const bf16x8*)(B0l + boff[fj] + k0);
            bf16x8 b1h = *(const bf16x8*)(B1h + boff[fj] + k0);
            bf16x8 b1l = *(const bf16x8*)(B1l + boff[fj] + k0);
#pragma unroll
            for (int fi = 0; fi < 4; fi++) {
                acc0[fi][fj] = __builtin_amdgcn_mfma_f32_16x16x32_bf16(fAh[fi], b0h, acc0[fi][fj], 0, 0, 0);
                acc0[fi][fj] = __builtin_amdgcn_mfma_f32_16x16x32_bf16(fAh[fi], b0l, acc0[fi][fj], 0, 0, 0);
                acc0[fi][fj] = __builtin_amdgcn_mfma_f32_16x16x32_bf16(fAl[fi], b0h, acc0[fi][fj], 0, 0, 0);
                acc1[fi][fj] = __builtin_amdgcn_mfma_f32_16x16x32_bf16(fAh[fi], b1h, acc1[fi][fj], 0, 0, 0);
                acc1[fi][fj] = __builtin_amdgcn_mfma_f32_16x16x32_bf16(fAh[fi], b1l, acc1[fi][fj], 0, 0, 0);
                acc1[fi][fj] = __builtin_amdgcn_mfma_f32_16x16x32_bf16(fAl[fi], b1h, acc1[fi][fj], 0, 0, 0);
            }
        }
        __syncthreads();
    }

#pragma unroll
    for (int fj = 0; fj < 4; fj++) {
        int gc = col0 + wc * 64 + fj * 16 + rr;
        if (gc >= N) continue;
        float bb0 = bias0 ? bias0[gc] : 0.f;
        float bb1 = bias1 ? bias1[gc] : 0.f;
#pragma unroll
        for (int fi = 0; fi < 4; fi++) {
#pragma unroll
            for (int r = 0; r < 4; r++) {
                int grr = row0 + wr * 64 + fi * 16 + quad * 4 + r;
                if (grr < M) {
                    float v0 = acc0[fi][fj][r] + bb0;
                    float v1 = acc1[fi][fj][r] + bb1;
                    if (fmt & 1) ((u16*)C0v)[(size_t)grr * 256 + gc] = f2h(v0);
                    else         ((float*)C0v)[(size_t)grr * N + gc] = v0;
                    if (fmt & 2) ((u16*)C1v)[(size_t)grr * 256 + gc] = f2h(v1);
                    else         ((float*)C1v)[(size_t)grr * N + gc] = v1;
                }
            }
        }
    }
}

// ---------------- fused edge phase: packed-fp16 single-pass softmax+aggregate ----------------
// 4-edge unroll full-wave. Wave-uniform scalarization: beg/end/ssrc offsets go through
// readfirstlane so edge offsets live in SGPRs (s_load + saddr addressing, ~0 VALU/load).

__global__ __launch_bounds__(256) void fused_edge_kernel(
    const int* __restrict__ rowptr, const int* __restrict__ ssrc,
    const u16* __restrict__ xl16, const float* __restrict__ xr,
    const float* __restrict__ att,
    u16* __restrict__ Oh, u16* __restrict__ Ol, int dorelu)
{
    int i = blockIdx.x * 4 + (threadIdx.x >> 6);
    if (i >= NN) return;
    int lane = threadIdx.x & 63;
    int beg = __builtin_amdgcn_readfirstlane(rowptr[i]);
    int end = __builtin_amdgcn_readfirstlane(rowptr[i + 1]);
    int d0 = lane * 4;
    int lb = d0 * 2;                 // lane byte offset into fp16 row

    // masked fp32 loads of xr/att for this lane's 4 dims, converted to fp16 pairs
    float xrf[4] = {0.f, 0.f, 0.f, 0.f};
    float atf[4] = {0.f, 0.f, 0.f, 0.f};
#pragma unroll
    for (int j = 0; j < 4; j++) {
        if (d0 + j < DD) {
            xrf[j] = xr[(size_t)i * DD + d0 + j];
            atf[j] = att[d0 + j];
        }
    }
    h2v xr0h, xr1h, at0h, at1h;
    xr0h.x = (_Float16)xrf[0]; xr0h.y = (_Float16)xrf[1];
    xr1h.x = (_Float16)xrf[2]; xr1h.y = (_Float16)xrf[3];
    at0h.x = (_Float16)atf[0]; at0h.y = (_Float16)atf[1];
    at1h.x = (_Float16)atf[2]; at1h.y = (_Float16)atf[3];
    const h2v c02 = {(_Float16)0.2f, (_Float16)0.2f};

    const char* xlb = (const char*)xl16;

    float m = -1e30f, ssum = 0.f;
    float4 acc = make_float4(0.f, 0.f, 0.f, 0.f);

    int p = beg;
    for (; p + 3 < end; p += 4) {
        int o0 = __builtin_amdgcn_readfirstlane(ssrc[p]);
        int o1 = __builtin_amdgcn_readfirstlane(ssrc[p + 1]);
        int o2 = __builtin_amdgcn_readfirstlane(ssrc[p + 2]);
        int o3 = __builtin_amdgcn_readfirstlane(ssrc[p + 3]);
        uint2 r0 = *(const uint2*)(xlb + o0 + lb);
        uint2 r1 = *(const uint2*)(xlb + o1 + lb);
        uint2 r2 = *(const uint2*)(xlb + o2 + lb);
        uint2 r3 = *(const uint2*)(xlb + o3 + lb);
        h2v x00 = *(h2v*)&r0.x, x01 = *(h2v*)&r0.y;
        h2v x10 = *(h2v*)&r1.x, x11 = *(h2v*)&r1.y;
        h2v x20 = *(h2v*)&r2.x, x21 = *(h2v*)&r2.y;
        h2v x30 = *(h2v*)&r3.x, x31 = *(h2v*)&r3.y;

        h2v s;
        float e0, e1, e2, e3;
        s = x00 + xr0h; s = hmax2v(s, s * c02);
        e0 = __builtin_amdgcn_fdot2(s, at0h, 0.f, false);
        s = x01 + xr1h; s = hmax2v(s, s * c02);
        e0 = __builtin_amdgcn_fdot2(s, at1h, e0, false);
        s = x10 + xr0h; s = hmax2v(s, s * c02);
        e1 = __builtin_amdgcn_fdot2(s, at0h, 0.f, false);
        s = x11 + xr1h; s = hmax2v(s, s * c02);
        e1 = __builtin_amdgcn_fdot2(s, at1h, e1, false);
        s = x20 + xr0h; s = hmax2v(s, s * c02);
        e2 = __builtin_amdgcn_fdot2(s, at0h, 0.f, false);
        s = x21 + xr1h; s = hmax2v(s, s * c02);
        e2 = __builtin_amdgcn_fdot2(s, at1h, e2, false);
        s = x30 + xr0h; s = hmax2v(s, s * c02);
        e3 = __builtin_amdgcn_fdot2(s, at0h, 0.f, false);
        s = x31 + xr1h; s = hmax2v(s, s * c02);
        e3 = __builtin_amdgcn_fdot2(s, at1h, e3, false);

#pragma unroll
        for (int off = 1; off < 64; off <<= 1) {
            e0 += __shfl_xor(e0, off, 64);
            e1 += __shfl_xor(e1, off, 64);
            e2 += __shfl_xor(e2, off, 64);
            e3 += __shfl_xor(e3, off, 64);
        }
        float nm = fmaxf(fmaxf(m, e0), fmaxf(fmaxf(e1, e2), e3));
        float sc = __expf(m - nm);
        float w0 = __expf(e0 - nm);
        float w1 = __expf(e1 - nm);
        float w2 = __expf(e2 - nm);
        float w3 = __expf(e3 - nm);
        // tree-paired accumulate (short dep chains; fma_mix folds the h->f cvt)
        float ax0 = fmaf(w1, (float)x10.x, w0 * (float)x00.x);
        float ax1 = fmaf(w3, (float)x30.x, w2 * (float)x20.x);
        float ay0 = fmaf(w1, (float)x10.y, w0 * (float)x00.y);
        float ay1 = fmaf(w3, (float)x30.y, w2 * (float)x20.y);
        float az0 = fmaf(w1, (float)x11.x, w0 * (float)x01.x);
        float az1 = fmaf(w3, (float)x31.x, w2 * (float)x21.x);
        float aw0 = fmaf(w1, (float)x11.y, w0 * (float)x01.y);
        float aw1 = fmaf(w3, (float)x31.y, w2 * (float)x21.y);
        acc.x = fmaf(acc.x, sc, ax0 + ax1);
        acc.y = fmaf(acc.y, sc, ay0 + ay1);
        acc.z = fmaf(acc.z, sc, az0 + az1);
        acc.w = fmaf(acc.w, sc, aw0 + aw1);
        ssum = fmaf(ssum, sc, (w0 + w1) + (w2 + w3));
        m = nm;
    }
    for (; p < end; p++) {
        int o = __builtin_amdgcn_readfirstlane(ssrc[p]);
        uint2 r = *(const uint2*)(xlb + o + lb);
        h2v x0 = *(h2v*)&r.x, x1 = *(h2v*)&r.y;
        h2v s;
        float e;
        s = x0 + xr0h; s = hmax2v(s, s * c02);
        e = __builtin_amdgcn_fdot2(s, at0h, 0.f, false);
        s = x1 + xr1h; s = hmax2v(s, s * c02);
        e = __builtin_amdgcn_fdot2(s, at1h, e, false);
#pragma unroll
        for (int off = 1; off < 64; off <<= 1)
            e += __shfl_xor(e, off, 64);
        float nm = fmaxf(m, e);
        float sc = __expf(m - nm);
        float w = __expf(e - nm);
        acc.x = fmaf(w, (float)x0.x, acc.x * sc);
        acc.y = fmaf(w, (float)x0.y, acc.y * sc);
        acc.z = fmaf(w, (float)x1.x, acc.z * sc);
        acc.w = fmaf(w, (float)x1.y, acc.w * sc);
        ssum = fmaf(ssum, sc, w);
        m = nm;
    }

    float inv = 1.f / ssum;
    acc.x *= inv; acc.y *= inv; acc.z *= inv; acc.w *= inv;
    if (dorelu) {
        acc.x = fmaxf(acc.x, 0.f); acc.y = fmaxf(acc.y, 0.f);
        acc.z = fmaxf(acc.z, 0.f); acc.w = fmaxf(acc.w, 0.f);
    }
    size_t base = (size_t)i * 256 + d0;
    u16 hx, lx, hy, ly, hz, lz, hw, lw;
    split2(acc.x, hx, lx); split2(acc.y, hy, ly);
    split2(acc.z, hz, lz); split2(acc.w, hw, lw);
    ushort4 hv; hv.x = hx; hv.y = hy; hv.z = hz; hv.w = hw;
    ushort4 lv; lv.x = lx; lv.y = ly; lv.z = lz; lv.w = lw;
    *(ushort4*)&Oh[base] = hv;
    *(ushort4*)&Ol[base] = lv;
}

// ---------------- query head: 2 queries per wave; fp16 gathers; uniform indices ----------------

__global__ __launch_bounds__(256) void query_kernel(
    const int* __restrict__ qry, const u16* __restrict__ Ptop,
    const u16* __restrict__ Pbot, const float* __restrict__ Wm2,
    const float* __restrict__ bm2, float* __restrict__ out)
{
    int q = (blockIdx.x * 4 + (threadIdx.x >> 6)) * 2;
    if (q >= NQ) return;
    int lane = threadIdx.x & 63;
    int a0 = __builtin_amdgcn_readfirstlane(qry[q * 2 + 0]);
    int b0 = __builtin_amdgcn_readfirstlane(qry[q * 2 + 1]);
    int a1 = __builtin_amdgcn_readfirstlane(qry[q * 2 + 2]);
    int b1 = __builtin_amdgcn_readfirstlane(qry[q * 2 + 3]);
    float4 w  = *(const float4*)&Wm2[lane * 4];
    float4 t0 = ld4h(&Ptop[(size_t)a0 * HD + lane * 4]);
    float4 v0 = ld4h(&Pbot[(size_t)b0 * HD + lane * 4]);
    float4 t1 = ld4h(&Ptop[(size_t)a1 * HD + lane * 4]);
    float4 v1 = ld4h(&Pbot[(size_t)b1 * HD + lane * 4]);
    float s0 = fmaxf(t0.x + v0.x, 0.f) * w.x + fmaxf(t0.y + v0.y, 0.f) * w.y
             + fmaxf(t0.z + v0.z, 0.f) * w.z + fmaxf(t0.w + v0.w, 0.f) * w.w;
    float s1 = fmaxf(t1.x + v1.x, 0.f) * w.x + fmaxf(t1.y + v1.y, 0.f) * w.y
             + fmaxf(t1.z + v1.z, 0.f) * w.z + fmaxf(t1.w + v1.w, 0.f) * w.w;
#pragma unroll
    for (int off = 32; off > 0; off >>= 1) {
        s0 += __shfl_down(s0, off, 64);
        s1 += __shfl_down(s1, off, 64);
    }
    if (lane == 0) {
        float bb = bm2[0];
        out[q] = fmaxf(s0 + bb, 0.f);
        if (q + 1 < NQ) out[q + 1] = fmaxf(s1 + bb, 0.f);
    }
}

// ---------------- launch ----------------

extern "C" void kernel_launch(void* const* d_in, const int* in_sizes, int n_in,
                              void* d_out, int out_size, void* d_ws, size_t ws_size,
                              hipStream_t stream) {
    const float* x    = (const float*)d_in[0];
    const int*   ei   = (const int*)d_in[1];
    const int*   qry  = (const int*)d_in[2];
    const float* W1l  = (const float*)d_in[3];
    const float* b1l  = (const float*)d_in[4];
    const float* W1r  = (const float*)d_in[5];
    const float* b1r  = (const float*)d_in[6];
    const float* att1 = (const float*)d_in[7];
    const float* W2l  = (const float*)d_in[8];
    const float* b2l  = (const float*)d_in[9];
    const float* W2r  = (const float*)d_in[10];
    const float* b2r  = (const float*)d_in[11];
    const float* att2 = (const float*)d_in[12];
    const float* Wm1  = (const float*)d_in[13];
    const float* bm1  = (const float*)d_in[14];
    const float* Wm2  = (const float*)d_in[15];
    const float* bm2  = (const float*)d_in[16];
    float* out = (float*)d_out;

    // workspace carve-up
    const size_t NND = (size_t)NN * DD;          // 12.5M floats
    u16* xl16    = (u16*)d_ws;                   // NN*256 halfs (25.6 MB)
    float* xr    = (float*)(xl16 + (size_t)NN * 256);  // NN*250 floats (50 MB)
    int* rowptr  = (int*)(xr + NND);             // NN+1
    int* fill    = rowptr + NN + 1;              // NN (count buffer)
    int* ssrc    = fill + NN;                    // ET
    int* bsum    = ssrc + ET;                    // 256
    uintptr_t wp = (uintptr_t)(bsum + 256);
    wp = (wp + 63) & ~(uintptr_t)63;
    u16* W1lTh = (u16*)wp;                       // 256*128 each
    u16* W1lTl = W1lTh + 256 * 128;
    u16* W1rTh = W1lTl + 256 * 128;
    u16* W1rTl = W1rTh + 256 * 128;
    u16* W2lTh = W1rTl + 256 * 128;              // 256*256 each from here
    u16* W2lTl = W2lTh + 65536;
    u16* W2rTh = W2lTl + 65536;
    u16* W2rTl = W2rTh + 65536;
    u16* WmtTh = W2rTl + 65536;
    u16* WmtTl = WmtTh + 65536;
    u16* WmbTh = WmtTl + 65536;
    u16* WmbTl = WmbTh + 65536;
    u16* Asph  = WmbTl + 65536;                  // NN*256 (also holds x-split [NN][128] early)
    u16* Aspl  = Asph + (size_t)NN * 256;
    // head fp16 buffers overlay xl16 / xr (both dead after layer-2 fused_edge)
    u16* Ptop16 = xl16;                          // NN*256 halfs
    u16* Pbot16 = (u16*)xr;                      // NN*256 halfs

    dim3 blk(256);
    int gET = (ET + 255) / 256;
    int gNode = (NN + 3) / 4;
    int nb = (NN + 255) / 256;                   // 196 scan blocks
    dim3 gg((NN + 127) / 128, 2);

    // ---- conversions + fill zeroing (one dispatch) ----
    conv_all<<<CONVX_BLOCKS + 1280, blk, 0, stream>>>(x, fill, Asph, Aspl,
        W1l, W1r, W2l, W2r, Wm1,
        W1lTh, W1lTl, W1rTh, W1rTl, W2lTh, W2lTl, W2rTh, W2rTl,
        WmtTh, WmtTl, WmbTh, WmbTl);

    // ---- CSR build ----
    count_kernel<<<gET, blk, 0, stream>>>(ei, fill);
    scan1_kernel<<<nb, blk, 0, stream>>>(fill, rowptr, bsum);   // also zeroes fill
    scan2_kernel<<<1, blk, 0, stream>>>(bsum, rowptr, nb);
    scan3_kernel<<<nb, blk, 0, stream>>>(rowptr, bsum);
    scatter_kernel<<<gET, blk, 0, stream>>>(ei, rowptr, fill, ssrc);

    // ---- layer 1 (A = x-split, Kp=128): C0 = xl fp16, C1 = xr fp32 ----
    gemm_pair<<<gg, blk, 0, stream>>>(Asph, Aspl, 128, W1lTh, W1lTl, W1rTh, W1rTl,
                                      b1l, b1r, (void*)xl16, (void*)xr, NN, DD, 1);
    fused_edge_kernel<<<gNode, blk, 0, stream>>>(rowptr, ssrc, xl16, xr, att1, Asph, Aspl, 1);

    // ---- layer 2 (A = h-split, Kp=256) ----
    gemm_pair<<<gg, blk, 0, stream>>>(Asph, Aspl, 256, W2lTh, W2lTl, W2rTh, W2rTl,
                                      b2l, b2r, (void*)xl16, (void*)xr, NN, DD, 1);
    fused_edge_kernel<<<gNode, blk, 0, stream>>>(rowptr, ssrc, xl16, xr, att2, Asph, Aspl, 0);

    // ---- head precompute (A = emb-split, Kp=256): both outputs fp16 ----
    gemm_pair<<<gg, blk, 0, stream>>>(Asph, Aspl, 256, WmtTh, WmtTl, WmbTh, WmbTl,
                                      bm1, (const float*)nullptr, (void*)Ptop16, (void*)Pbot16, NN, HD, 3);

    // ---- per-query head ----
    query_kernel<<<(NQ / 2 + 3) / 4, blk, 0, stream>>>(qry, Ptop16, Pbot16, Wm2, bm2, out);
}

// Round 17
// 571.826 us; speedup vs baseline: 1.1329x; 1.1329x over previous
//
#include <hip/hip_runtime.h>
#include <hip/hip_fp16.h>
#include <math.h>
#include <stdint.h>

#define NN 50000
#define NE 800000
#define ET (NE + NN)      // 850000 edges incl self loops
#define FIN 128
#define DD 250
#define HD 256
#define NQ 200000
#define NEG_SLOPE 0.2f

typedef unsigned short u16;
typedef __attribute__((ext_vector_type(8))) short bf16x8;
typedef __attribute__((ext_vector_type(4))) float f32x4;
typedef _Float16 h2v __attribute__((ext_vector_type(2)));

__device__ __forceinline__ u16 f2bf_rne(float x) {
    unsigned int b = __float_as_uint(x);
    unsigned int r = (b + 0x7FFFu + ((b >> 16) & 1u)) >> 16;
    return (u16)r;
}
__device__ __forceinline__ void split2(float v, u16& h, u16& l) {
    unsigned int b = __float_as_uint(v);
    h = (u16)(b >> 16);
    float r = v - __uint_as_float(b & 0xFFFF0000u);
    l = f2bf_rne(r);
}
__device__ __forceinline__ u16 f2h(float v) {
    __half h = __float2half(v);
    return *reinterpret_cast<u16*>(&h);
}
// load 4 fp16 (8B) -> float4 (used by query kernel)
__device__ __forceinline__ float4 ld4h(const u16* p) {
    uint2 r = *(const uint2*)p;
    __half2 a = *(__half2*)&r.x;
    __half2 b = *(__half2*)&r.y;
    float2 fa = __half22float2(a), fb = __half22float2(b);
    return make_float4(fa.x, fa.y, fb.x, fb.y);
}
// packed fp16 max -> v_pk_max_f16 (avoids ROCm __hmax2 header overload issues)
__device__ __forceinline__ h2v hmax2v(h2v a, h2v b) {
    return __builtin_elementwise_max(a, b);
}

// ---------------- CSR build ----------------

__global__ void count_kernel(const int* __restrict__ ei, int* __restrict__ cnt) {
    int k = blockIdx.x * 256 + threadIdx.x;
    if (k >= ET) return;
    int d = (k < NE) ? ei[NE + k] : (k - NE);
    atomicAdd(&cnt[d], 1);
}

__global__ __launch_bounds__(256) void scan1_kernel(
    int* __restrict__ cnt, int* __restrict__ rowptr, int* __restrict__ bsum)
{
    __shared__ int buf[256];
    int t = threadIdx.x;
    int i = blockIdx.x * 256 + t;
    int v = (i < NN) ? cnt[i] : 0;
    if (i < NN) cnt[i] = 0;          // zero fill for scatter
    buf[t] = v;
    __syncthreads();
#pragma unroll
    for (int off = 1; off < 256; off <<= 1) {
        int add = (t >= off) ? buf[t - off] : 0;
        __syncthreads();
        buf[t] += add;
        __syncthreads();
    }
    if (i < NN) rowptr[i] = buf[t] - v;     // block-local exclusive
    if (t == 255) bsum[blockIdx.x] = buf[255];
}

__global__ __launch_bounds__(256) void scan2_kernel(
    int* __restrict__ bsum, int* __restrict__ rowptr, int nb)
{
    __shared__ int buf[256];
    int t = threadIdx.x;
    int v = (t < nb) ? bsum[t] : 0;
    buf[t] = v;
    __syncthreads();
#pragma unroll
    for (int off = 1; off < 256; off <<= 1) {
        int add = (t >= off) ? buf[t - off] : 0;
        __syncthreads();
        buf[t] += add;
        __syncthreads();
    }
    if (t < nb) bsum[t] = buf[t] - v;
    if (t == 255) rowptr[NN] = buf[255];
}

__global__ __launch_bounds__(256) void scan3_kernel(
    int* __restrict__ rowptr, const int* __restrict__ bsum)
{
    int i = blockIdx.x * 256 + threadIdx.x;
    if (i < NN) rowptr[i] += bsum[blockIdx.x];
}

// stores premultiplied src BYTE offset (s*512, fp16-row stride) for the fused kernel
__global__ void scatter_kernel(const int* __restrict__ ei,
                               const int* __restrict__ rowptr,
                               int* __restrict__ fill,
                               int* __restrict__ ssrc) {
    int k = blockIdx.x * 256 + threadIdx.x;
    if (k >= ET) return;
    int s, d;
    if (k < NE) { s = ei[k]; d = ei[NE + k]; }
    else        { s = k - NE; d = k - NE; }
    int pos = rowptr[d] + atomicAdd(&fill[d], 1);
    ssrc[pos] = s << 9;
}

// ---------------- combined conversion kernel ----------------

#define CONVX_BLOCKS 3125

__global__ __launch_bounds__(256) void conv_all(
    const float* __restrict__ x, int* __restrict__ fill,
    u16* __restrict__ Ah, u16* __restrict__ Al,
    const float* __restrict__ W1l, const float* __restrict__ W1r,
    const float* __restrict__ W2l, const float* __restrict__ W2r,
    const float* __restrict__ Wm1,
    u16* __restrict__ W1lTh, u16* __restrict__ W1lTl,
    u16* __restrict__ W1rTh, u16* __restrict__ W1rTl,
    u16* __restrict__ W2lTh, u16* __restrict__ W2lTl,
    u16* __restrict__ W2rTh, u16* __restrict__ W2rTl,
    u16* __restrict__ WmtTh, u16* __restrict__ WmtTl,
    u16* __restrict__ WmbTh, u16* __restrict__ WmbTl)
{
    if (blockIdx.x < CONVX_BLOCKS) {
        int tid = blockIdx.x * 256 + threadIdx.x;
        if (tid < NN) fill[tid] = 0;
        size_t idx = (size_t)tid * 8;
        if (idx >= (size_t)NN * FIN) return;
        float4 v0 = *(const float4*)(x + idx);
        float4 v1 = *(const float4*)(x + idx + 4);
        float vv[8] = {v0.x, v0.y, v0.z, v0.w, v1.x, v1.y, v1.z, v1.w};
        bf16x8 h, l;
#pragma unroll
        for (int j = 0; j < 8; j++) {
            u16 hh, ll;
            split2(vv[j], hh, ll);
            h[j] = (short)hh; l[j] = (short)ll;
        }
        *(bf16x8*)(Ah + idx) = h;
        *(bf16x8*)(Al + idx) = l;
        return;
    }
    int b = blockIdx.x - CONVX_BLOCKS;
    const float* W; int K, N, koff, kshift, b0; u16 *oh, *ol;
    if (b < 128)       { W = W1l; K = FIN; N = DD; koff = 0;  kshift = 7; b0 = 0;    oh = W1lTh; ol = W1lTl; }
    else if (b < 256)  { W = W1r; K = FIN; N = DD; koff = 0;  kshift = 7; b0 = 128;  oh = W1rTh; ol = W1rTl; }
    else if (b < 512)  { W = W2l; K = DD;  N = DD; koff = 0;  kshift = 8; b0 = 256;  oh = W2lTh; ol = W2lTl; }
    else if (b < 768)  { W = W2r; K = DD;  N = DD; koff = 0;  kshift = 8; b0 = 512;  oh = W2rTh; ol = W2rTl; }
    else if (b < 1024) { W = Wm1; K = DD;  N = HD; koff = 0;  kshift = 8; b0 = 768;  oh = WmtTh; ol = WmtTl; }
    else               { W = Wm1; K = DD;  N = HD; koff = DD; kshift = 8; b0 = 1024; oh = WmbTh; ol = WmbTl; }
    int id = (b - b0) * 256 + threadIdx.x;
    int Kp = 1 << kshift;
    int n = id >> kshift, k = id & (Kp - 1);
    float v = (n < N && k < K) ? W[(size_t)(k + koff) * N + n] : 0.f;
    u16 h, l;
    split2(v, h, l);
    oh[id] = h;
    ol[id] = l;
}

// ---------------- pre-split bf16 MFMA pair-GEMM ----------------
// A and B staged in LDS with rows padded 32->40 u16 (8 distinct 4-bank write
// starts -> ~3x fewer bank conflicts, measured R15). B-direct-global was tried
// (R15) and regressed badly: B fragment loads are 512B-strided uncoalesced.
// fmt bit0: C0 as fp16 stride-256; bit1: C1 as fp16 stride-256; else fp32 stride-N

#define AP 40   // padded LDS row length (u16)

__global__ __launch_bounds__(256, 2) void gemm_pair(
    const u16* __restrict__ Ah, const u16* __restrict__ Al, int Kp,
    const u16* __restrict__ B0h, const u16* __restrict__ B0l,
    const u16* __restrict__ B1h, const u16* __restrict__ B1l,
    const float* __restrict__ bias0, const float* __restrict__ bias1,
    void* __restrict__ C0v, void* __restrict__ C1v, int M, int N, int fmt)
{
    __shared__ u16 AhS[128][AP], AlS[128][AP];
    __shared__ u16 BhS[2][128][AP], BlS[2][128][AP];

    int row0 = blockIdx.x * 128;
    int col0 = blockIdx.y * 128;
    int t = threadIdx.x;
    int lane = t & 63, w = t >> 6;
    int wr = w >> 1, wc = w & 1;
    int quad = lane >> 4, rr = lane & 15;

    f32x4 acc0[4][4], acc1[4][4];
#pragma unroll
    for (int i = 0; i < 4; i++)
#pragma unroll
        for (int j = 0; j < 4; j++) {
            acc0[i][j] = (f32x4){0.f, 0.f, 0.f, 0.f};
            acc1[i][j] = (f32x4){0.f, 0.f, 0.f, 0.f};
        }

    int ar = t >> 1, akh = (t & 1) * 16;
    int gr = row0 + ar;
    int nB = col0 + ar;
    const u16* pAh = Ah + (size_t)gr * Kp + akh;
    const u16* pAl = Al + (size_t)gr * Kp + akh;
    const u16* pB0h = B0h + (size_t)nB * Kp + akh;
    const u16* pB0l = B0l + (size_t)nB * Kp + akh;
    const u16* pB1h = B1h + (size_t)nB * Kp + akh;
    const u16* pB1l = B1l + (size_t)nB * Kp + akh;

    for (int k0 = 0; k0 < Kp; k0 += 32) {
        bf16x8 ah0{}, ah1{}, al0{}, al1{};
        if (gr < M) {
            ah0 = *(const bf16x8*)(pAh + k0);
            ah1 = *(const bf16x8*)(pAh + k0 + 8);
            al0 = *(const bf16x8*)(pAl + k0);
            al1 = *(const bf16x8*)(pAl + k0 + 8);
        }
        *(bf16x8*)&AhS[ar][akh]     = ah0;
        *(bf16x8*)&AhS[ar][akh + 8] = ah1;
        *(bf16x8*)&AlS[ar][akh]     = al0;
        *(bf16x8*)&AlS[ar][akh + 8] = al1;
        *(bf16x8*)&BhS[0][ar][akh]     = *(const bf16x8*)(pB0h + k0);
        *(bf16x8*)&BhS[0][ar][akh + 8] = *(const bf16x8*)(pB0h + k0 + 8);
        *(bf16x8*)&BlS[0][ar][akh]     = *(const bf16x8*)(pB0l + k0);
        *(bf16x8*)&BlS[0][ar][akh + 8] = *(const bf16x8*)(pB0l + k0 + 8);
        *(bf16x8*)&BhS[1][ar][akh]     = *(const bf16x8*)(pB1h + k0);
        *(bf16x8*)&BhS[1][ar][akh + 8] = *(const bf16x8*)(pB1h + k0 + 8);
        *(bf16x8*)&BlS[1][ar][akh]     = *(const bf16x8*)(pB1l + k0);
        *(bf16x8*)&BlS[1][ar][akh + 8] = *(const bf16x8*)(pB1l + k0 + 8);
        __syncthreads();

        bf16x8 fAh[4], fAl[4];
#pragma unroll
        for (int fi = 0; fi < 4; fi++) {
            int r = wr * 64 + fi * 16 + rr;
            fAh[fi] = *(const bf16x8*)&AhS[r][quad * 8];
            fAl[fi] = *(const bf16x8*)&AlS[r][quad * 8];
        }
#pragma unroll
        for (int fj = 0; fj < 4; fj++) {
            int c = wc * 64 + fj * 16 + rr;
            bf16x8 b0h = *(const bf16x8*)&BhS[0][c][quad * 8];
            bf16x8 b0l = *(const bf16x8*)&BlS[0][c][quad * 8];
            bf16x8 b1h = *(const bf16x8*)&BhS[1][c][quad * 8];
            bf16x8 b1l = *(const bf16x8*)&BlS[1][c][quad * 8];
#pragma unroll
            for (int fi = 0; fi < 4; fi++) {
                acc0[fi][fj] = __builtin_amdgcn_mfma_f32_16x16x32_bf16(fAh[fi], b0h, acc0[fi][fj], 0, 0, 0);
                acc0[fi][fj] = __builtin_amdgcn_mfma_f32_16x16x32_bf16(fAh[fi], b0l, acc0[fi][fj], 0, 0, 0);
                acc0[fi][fj] = __builtin_amdgcn_mfma_f32_16x16x32_bf16(fAl[fi], b0h, acc0[fi][fj], 0, 0, 0);
                acc1[fi][fj] = __builtin_amdgcn_mfma_f32_16x16x32_bf16(fAh[fi], b1h, acc1[fi][fj], 0, 0, 0);
                acc1[fi][fj] = __builtin_amdgcn_mfma_f32_16x16x32_bf16(fAh[fi], b1l, acc1[fi][fj], 0, 0, 0);
                acc1[fi][fj] = __builtin_amdgcn_mfma_f32_16x16x32_bf16(fAl[fi], b1h, acc1[fi][fj], 0, 0, 0);
            }
        }
        __syncthreads();
    }

#pragma unroll
    for (int fj = 0; fj < 4; fj++) {
        int gc = col0 + wc * 64 + fj * 16 + rr;
        if (gc >= N) continue;
        float bb0 = bias0 ? bias0[gc] : 0.f;
        float bb1 = bias1 ? bias1[gc] : 0.f;
#pragma unroll
        for (int fi = 0; fi < 4; fi++) {
#pragma unroll
            for (int r = 0; r < 4; r++) {
                int grr = row0 + wr * 64 + fi * 16 + quad * 4 + r;
                if (grr < M) {
                    float v0 = acc0[fi][fj][r] + bb0;
                    float v1 = acc1[fi][fj][r] + bb1;
                    if (fmt & 1) ((u16*)C0v)[(size_t)grr * 256 + gc] = f2h(v0);
                    else         ((float*)C0v)[(size_t)grr * N + gc] = v0;
                    if (fmt & 2) ((u16*)C1v)[(size_t)grr * 256 + gc] = f2h(v1);
                    else         ((float*)C1v)[(size_t)grr * N + gc] = v1;
                }
            }
        }
    }
}

// ---------------- fused edge phase: packed-fp16 single-pass softmax+aggregate ----------------
// 4-edge unroll full-wave. Wave-uniform scalarization: beg/end/ssrc offsets go through
// readfirstlane so edge offsets live in SGPRs (s_load + saddr addressing, ~0 VALU/load).

__global__ __launch_bounds__(256) void fused_edge_kernel(
    const int* __restrict__ rowptr, const int* __restrict__ ssrc,
    const u16* __restrict__ xl16, const float* __restrict__ xr,
    const float* __restrict__ att,
    u16* __restrict__ Oh, u16* __restrict__ Ol, int dorelu)
{
    int i = blockIdx.x * 4 + (threadIdx.x >> 6);
    if (i >= NN) return;
    int lane = threadIdx.x & 63;
    int beg = __builtin_amdgcn_readfirstlane(rowptr[i]);
    int end = __builtin_amdgcn_readfirstlane(rowptr[i + 1]);
    int d0 = lane * 4;
    int lb = d0 * 2;                 // lane byte offset into fp16 row

    // masked fp32 loads of xr/att for this lane's 4 dims, converted to fp16 pairs
    float xrf[4] = {0.f, 0.f, 0.f, 0.f};
    float atf[4] = {0.f, 0.f, 0.f, 0.f};
#pragma unroll
    for (int j = 0; j < 4; j++) {
        if (d0 + j < DD) {
            xrf[j] = xr[(size_t)i * DD + d0 + j];
            atf[j] = att[d0 + j];
        }
    }
    h2v xr0h, xr1h, at0h, at1h;
    xr0h.x = (_Float16)xrf[0]; xr0h.y = (_Float16)xrf[1];
    xr1h.x = (_Float16)xrf[2]; xr1h.y = (_Float16)xrf[3];
    at0h.x = (_Float16)atf[0]; at0h.y = (_Float16)atf[1];
    at1h.x = (_Float16)atf[2]; at1h.y = (_Float16)atf[3];
    const h2v c02 = {(_Float16)0.2f, (_Float16)0.2f};

    const char* xlb = (const char*)xl16;

    float m = -1e30f, ssum = 0.f;
    float4 acc = make_float4(0.f, 0.f, 0.f, 0.f);

    int p = beg;
    for (; p + 3 < end; p += 4) {
        int o0 = __builtin_amdgcn_readfirstlane(ssrc[p]);
        int o1 = __builtin_amdgcn_readfirstlane(ssrc[p + 1]);
        int o2 = __builtin_amdgcn_readfirstlane(ssrc[p + 2]);
        int o3 = __builtin_amdgcn_readfirstlane(ssrc[p + 3]);
        uint2 r0 = *(const uint2*)(xlb + o0 + lb);
        uint2 r1 = *(const uint2*)(xlb + o1 + lb);
        uint2 r2 = *(const uint2*)(xlb + o2 + lb);
        uint2 r3 = *(const uint2*)(xlb + o3 + lb);
        h2v x00 = *(h2v*)&r0.x, x01 = *(h2v*)&r0.y;
        h2v x10 = *(h2v*)&r1.x, x11 = *(h2v*)&r1.y;
        h2v x20 = *(h2v*)&r2.x, x21 = *(h2v*)&r2.y;
        h2v x30 = *(h2v*)&r3.x, x31 = *(h2v*)&r3.y;

        h2v s;
        float e0, e1, e2, e3;
        s = x00 + xr0h; s = hmax2v(s, s * c02);
        e0 = __builtin_amdgcn_fdot2(s, at0h, 0.f, false);
        s = x01 + xr1h; s = hmax2v(s, s * c02);
        e0 = __builtin_amdgcn_fdot2(s, at1h, e0, false);
        s = x10 + xr0h; s = hmax2v(s, s * c02);
        e1 = __builtin_amdgcn_fdot2(s, at0h, 0.f, false);
        s = x11 + xr1h; s = hmax2v(s, s * c02);
        e1 = __builtin_amdgcn_fdot2(s, at1h, e1, false);
        s = x20 + xr0h; s = hmax2v(s, s * c02);
        e2 = __builtin_amdgcn_fdot2(s, at0h, 0.f, false);
        s = x21 + xr1h; s = hmax2v(s, s * c02);
        e2 = __builtin_amdgcn_fdot2(s, at1h, e2, false);
        s = x30 + xr0h; s = hmax2v(s, s * c02);
        e3 = __builtin_amdgcn_fdot2(s, at0h, 0.f, false);
        s = x31 + xr1h; s = hmax2v(s, s * c02);
        e3 = __builtin_amdgcn_fdot2(s, at1h, e3, false);

#pragma unroll
        for (int off = 1; off < 64; off <<= 1) {
            e0 += __shfl_xor(e0, off, 64);
            e1 += __shfl_xor(e1, off, 64);
            e2 += __shfl_xor(e2, off, 64);
            e3 += __shfl_xor(e3, off, 64);
        }
        float nm = fmaxf(fmaxf(m, e0), fmaxf(fmaxf(e1, e2), e3));
        float sc = __expf(m - nm);
        float w0 = __expf(e0 - nm);
        float w1 = __expf(e1 - nm);
        float w2 = __expf(e2 - nm);
        float w3 = __expf(e3 - nm);
        // tree-paired accumulate (short dep chains; fma_mix folds the h->f cvt)
        float ax0 = fmaf(w1, (float)x10.x, w0 * (float)x00.x);
        float ax1 = fmaf(w3, (float)x30.x, w2 * (float)x20.x);
        float ay0 = fmaf(w1, (float)x10.y, w0 * (float)x00.y);
        float ay1 = fmaf(w3, (float)x30.y, w2 * (float)x20.y);
        float az0 = fmaf(w1, (float)x11.x, w0 * (float)x01.x);
        float az1 = fmaf(w3, (float)x31.x, w2 * (float)x21.x);
        float aw0 = fmaf(w1, (float)x11.y, w0 * (float)x01.y);
        float aw1 = fmaf(w3, (float)x31.y, w2 * (float)x21.y);
        acc.x = fmaf(acc.x, sc, ax0 + ax1);
        acc.y = fmaf(acc.y, sc, ay0 + ay1);
        acc.z = fmaf(acc.z, sc, az0 + az1);
        acc.w = fmaf(acc.w, sc, aw0 + aw1);
        ssum = fmaf(ssum, sc, (w0 + w1) + (w2 + w3));
        m = nm;
    }
    for (; p < end; p++) {
        int o = __builtin_amdgcn_readfirstlane(ssrc[p]);
        uint2 r = *(const uint2*)(xlb + o + lb);
        h2v x0 = *(h2v*)&r.x, x1 = *(h2v*)&r.y;
        h2v s;
        float e;
        s = x0 + xr0h; s = hmax2v(s, s * c02);
        e = __builtin_amdgcn_fdot2(s, at0h, 0.f, false);
        s = x1 + xr1h; s = hmax2v(s, s * c02);
        e = __builtin_amdgcn_fdot2(s, at1h, e, false);
#pragma unroll
        for (int off = 1; off < 64; off <<= 1)
            e += __shfl_xor(e, off, 64);
        float nm = fmaxf(m, e);
        float sc = __expf(m - nm);
        float w = __expf(e - nm);
        acc.x = fmaf(w, (float)x0.x, acc.x * sc);
        acc.y = fmaf(w, (float)x0.y, acc.y * sc);
        acc.z = fmaf(w, (float)x1.x, acc.z * sc);
        acc.w = fmaf(w, (float)x1.y, acc.w * sc);
        ssum = fmaf(ssum, sc, w);
        m = nm;
    }

    float inv = 1.f / ssum;
    acc.x *= inv; acc.y *= inv; acc.z *= inv; acc.w *= inv;
    if (dorelu) {
        acc.x = fmaxf(acc.x, 0.f); acc.y = fmaxf(acc.y, 0.f);
        acc.z = fmaxf(acc.z, 0.f); acc.w = fmaxf(acc.w, 0.f);
    }
    size_t base = (size_t)i * 256 + d0;
    u16 hx, lx, hy, ly, hz, lz, hw, lw;
    split2(acc.x, hx, lx); split2(acc.y, hy, ly);
    split2(acc.z, hz, lz); split2(acc.w, hw, lw);
    ushort4 hv; hv.x = hx; hv.y = hy; hv.z = hz; hv.w = hw;
    ushort4 lv; lv.x = lx; lv.y = ly; lv.z = lz; lv.w = lw;
    *(ushort4*)&Oh[base] = hv;
    *(ushort4*)&Ol[base] = lv;
}

// ---------------- query head: 2 queries per wave; fp16 gathers; uniform indices ----------------

__global__ __launch_bounds__(256) void query_kernel(
    const int* __restrict__ qry, const u16* __restrict__ Ptop,
    const u16* __restrict__ Pbot, const float* __restrict__ Wm2,
    const float* __restrict__ bm2, float* __restrict__ out)
{
    int q = (blockIdx.x * 4 + (threadIdx.x >> 6)) * 2;
    if (q >= NQ) return;
    int lane = threadIdx.x & 63;
    int a0 = __builtin_amdgcn_readfirstlane(qry[q * 2 + 0]);
    int b0 = __builtin_amdgcn_readfirstlane(qry[q * 2 + 1]);
    int a1 = __builtin_amdgcn_readfirstlane(qry[q * 2 + 2]);
    int b1 = __builtin_amdgcn_readfirstlane(qry[q * 2 + 3]);
    float4 w  = *(const float4*)&Wm2[lane * 4];
    float4 t0 = ld4h(&Ptop[(size_t)a0 * HD + lane * 4]);
    float4 v0 = ld4h(&Pbot[(size_t)b0 * HD + lane * 4]);
    float4 t1 = ld4h(&Ptop[(size_t)a1 * HD + lane * 4]);
    float4 v1 = ld4h(&Pbot[(size_t)b1 * HD + lane * 4]);
    float s0 = fmaxf(t0.x + v0.x, 0.f) * w.x + fmaxf(t0.y + v0.y, 0.f) * w.y
             + fmaxf(t0.z + v0.z, 0.f) * w.z + fmaxf(t0.w + v0.w, 0.f) * w.w;
    float s1 = fmaxf(t1.x + v1.x, 0.f) * w.x + fmaxf(t1.y + v1.y, 0.f) * w.y
             + fmaxf(t1.z + v1.z, 0.f) * w.z + fmaxf(t1.w + v1.w, 0.f) * w.w;
#pragma unroll
    for (int off = 32; off > 0; off >>= 1) {
        s0 += __shfl_down(s0, off, 64);
        s1 += __shfl_down(s1, off, 64);
    }
    if (lane == 0) {
        float bb = bm2[0];
        out[q] = fmaxf(s0 + bb, 0.f);
        if (q + 1 < NQ) out[q + 1] = fmaxf(s1 + bb, 0.f);
    }
}

// ---------------- launch ----------------

extern "C" void kernel_launch(void* const* d_in, const int* in_sizes, int n_in,
                              void* d_out, int out_size, void* d_ws, size_t ws_size,
                              hipStream_t stream) {
    const float* x    = (const float*)d_in[0];
    const int*   ei   = (const int*)d_in[1];
    const int*   qry  = (const int*)d_in[2];
    const float* W1l  = (const float*)d_in[3];
    const float* b1l  = (const float*)d_in[4];
    const float* W1r  = (const float*)d_in[5];
    const float* b1r  = (const float*)d_in[6];
    const float* att1 = (const float*)d_in[7];
    const float* W2l  = (const float*)d_in[8];
    const float* b2l  = (const float*)d_in[9];
    const float* W2r  = (const float*)d_in[10];
    const float* b2r  = (const float*)d_in[11];
    const float* att2 = (const float*)d_in[12];
    const float* Wm1  = (const float*)d_in[13];
    const float* bm1  = (const float*)d_in[14];
    const float* Wm2  = (const float*)d_in[15];
    const float* bm2  = (const float*)d_in[16];
    float* out = (float*)d_out;

    // workspace carve-up
    const size_t NND = (size_t)NN * DD;          // 12.5M floats
    u16* xl16    = (u16*)d_ws;                   // NN*256 halfs (25.6 MB)
    float* xr    = (float*)(xl16 + (size_t)NN * 256);  // NN*250 floats (50 MB)
    int* rowptr  = (int*)(xr + NND);             // NN+1
    int* fill    = rowptr + NN + 1;              // NN (count buffer)
    int* ssrc    = fill + NN;                    // ET
    int* bsum    = ssrc + ET;                    // 256
    uintptr_t wp = (uintptr_t)(bsum + 256);
    wp = (wp + 63) & ~(uintptr_t)63;
    u16* W1lTh = (u16*)wp;                       // 256*128 each
    u16* W1lTl = W1lTh + 256 * 128;
    u16* W1rTh = W1lTl + 256 * 128;
    u16* W1rTl = W1rTh + 256 * 128;
    u16* W2lTh = W1rTl + 256 * 128;              // 256*256 each from here
    u16* W2lTl = W2lTh + 65536;
    u16* W2rTh = W2lTl + 65536;
    u16* W2rTl = W2rTh + 65536;
    u16* WmtTh = W2rTl + 65536;
    u16* WmtTl = WmtTh + 65536;
    u16* WmbTh = WmtTl + 65536;
    u16* WmbTl = WmbTh + 65536;
    u16* Asph  = WmbTl + 65536;                  // NN*256 (also holds x-split [NN][128] early)
    u16* Aspl  = Asph + (size_t)NN * 256;
    // head fp16 buffers overlay xl16 / xr (both dead after layer-2 fused_edge)
    u16* Ptop16 = xl16;                          // NN*256 halfs
    u16* Pbot16 = (u16*)xr;                      // NN*256 halfs

    dim3 blk(256);
    int gET = (ET + 255) / 256;
    int gNode = (NN + 3) / 4;
    int nb = (NN + 255) / 256;                   // 196 scan blocks
    dim3 gg((NN + 127) / 128, 2);

    // ---- conversions + fill zeroing (one dispatch) ----
    conv_all<<<CONVX_BLOCKS + 1280, blk, 0, stream>>>(x, fill, Asph, Aspl,
        W1l, W1r, W2l, W2r, Wm1,
        W1lTh, W1lTl, W1rTh, W1rTl, W2lTh, W2lTl, W2rTh, W2rTl,
        WmtTh, WmtTl, WmbTh, WmbTl);

    // ---- CSR build ----
    count_kernel<<<gET, blk, 0, stream>>>(ei, fill);
    scan1_kernel<<<nb, blk, 0, stream>>>(fill, rowptr, bsum);   // also zeroes fill
    scan2_kernel<<<1, blk, 0, stream>>>(bsum, rowptr, nb);
    scan3_kernel<<<nb, blk, 0, stream>>>(rowptr, bsum);
    scatter_kernel<<<gET, blk, 0, stream>>>(ei, rowptr, fill, ssrc);

    // ---- layer 1 (A = x-split, Kp=128): C0 = xl fp16, C1 = xr fp32 ----
    gemm_pair<<<gg, blk, 0, stream>>>(Asph, Aspl, 128, W1lTh, W1lTl, W1rTh, W1rTl,
                                      b1l, b1r, (void*)xl16, (void*)xr, NN, DD, 1);
    fused_edge_kernel<<<gNode, blk, 0, stream>>>(rowptr, ssrc, xl16, xr, att1, Asph, Aspl, 1);

    // ---- layer 2 (A = h-split, Kp=256) ----
    gemm_pair<<<gg, blk, 0, stream>>>(Asph, Aspl, 256, W2lTh, W2lTl, W2rTh, W2rTl,
                                      b2l, b2r, (void*)xl16, (void*)xr, NN, DD, 1);
    fused_edge_kernel<<<gNode, blk, 0, stream>>>(rowptr, ssrc, xl16, xr, att2, Asph, Aspl, 0);

    // ---- head precompute (A = emb-split, Kp=256): both outputs fp16 ----
    gemm_pair<<<gg, blk, 0, stream>>>(Asph, Aspl, 256, WmtTh, WmtTl, WmbTh, WmbTl,
                                      bm1, (const float*)nullptr, (void*)Ptop16, (void*)Pbot16, NN, HD, 3);

    // ---- per-query head ----
    query_kernel<<<(NQ / 2 + 3) / 4, blk, 0, stream>>>(qry, Ptop16, Pbot16, Wm2, bm2, out);
}